// Round 10
// baseline (385.492 us; speedup 1.0000x reference)
//
#include <hip/hip_runtime.h>
#include <hip/hip_bf16.h>

#define BB 16
#define NN 1024
#define FF 128
#define HH 192
#define NROWS (BB*NN)
#define MAXC 128
#define EPSV 1e-5f

// ---------------- workspace layout (float units) ----------------
constexpr size_t OFF_H0  = 0;                                 // [NROWS*HH] bf16
constexpr size_t OFF_ZB  = OFF_H0 + (size_t)NROWS*HH/2;       // [NROWS*HH] bf16
constexpr size_t OFF_DIS = OFF_ZB + (size_t)NROWS*HH/2;       // [NROWS] f32
constexpr size_t OFF_G   = OFF_DIS + NROWS;                   // [BB*HH] pool sums
constexpr size_t OFF_SH  = OFF_G + BB*HH;                     // 3 stages x 8 buckets x 512
constexpr size_t SH_SIZE = 3*8*512;
constexpr size_t ZERO_SZ = BB*HH + SH_SIZE;                   // zeroed in k_prep
constexpr size_t OFF_FLG = OFF_SH + SH_SIZE;                  // [0] isf flag, [1] done-counter
constexpr size_t OFF_PRM = OFF_FLG + 16;                      // f32 params [3584]
// prm: 0 fc_g,192 fc_b,384 lin_b,576 hid_g,768 hid_b,960 cls_b(10),
//      976 cls_W(1920), 2896 convs_b(576)
constexpr size_t OFF_WLT = OFF_PRM + 3584;                    // lin_W bf16 [HH*HH]
constexpr size_t OFF_XB  = OFF_WLT + (size_t)HH*HH/2;         // x-stat buckets [128][256]
constexpr size_t OFF_WPF = OFF_XB + 128*256;                  // RAW W_feat^T bf16 [192][128]
constexpr size_t OFF_WPC = OFF_WPF + (size_t)HH*FF/2;         // RAW convs_W^T bf16 [3][192][192]
constexpr size_t OFF_CNT = OFF_WPC + 3*(size_t)HH*HH/2;       // [NROWS] int32
constexpr size_t OFF_COLS= OFF_CNT + NROWS;                   // [NROWS*MAXC] u16

typedef __attribute__((ext_vector_type(8))) short short8;
typedef __attribute__((ext_vector_type(4))) float f32x4;
typedef __attribute__((ext_vector_type(4))) unsigned int u32x4;
typedef __attribute__((ext_vector_type(2))) unsigned int u32x2;

static __device__ __forceinline__ float ldin(const void* p, size_t i, int isf) {
    return isf ? ((const float*)p)[i]
               : __bfloat162float(((const __hip_bfloat16*)p)[i]);
}
static __device__ __forceinline__ float blo(unsigned int u) {
    union { unsigned int x; float f; } v; v.x = u << 16; return v.f;
}
static __device__ __forceinline__ float bhi(unsigned int u) {
    union { unsigned int x; float f; } v; v.x = u & 0xFFFF0000u; return v.f;
}
static __device__ __forceinline__ unsigned int packbf(float a, float b) {
    union { unsigned int u; __hip_bfloat16 h[2]; } p;
    p.h[0] = __float2bfloat16(a); p.h[1] = __float2bfloat16(b);
    return p.u;
}
static __device__ __forceinline__ unsigned short bf16bits(float a) {
    union { unsigned short u; __hip_bfloat16 h; } p;
    p.h = __float2bfloat16(a); return p.u;
}
static __device__ __forceinline__ int rdflag(const float* ws) {
    return ((const int*)(ws + OFF_FLG))[0];
}

// dtype self-detection — run ONLY inside k_prep; published to ws flag.
template<int T>
static __device__ __forceinline__ int detect_isf(const unsigned int* __restrict__ adjw,
                                                 int tid, int* sh_flag) {
    if (tid == 0) *sh_flag = 0;
    __syncthreads();
    int hit = 0;
    for (int k = tid; k < 1024; k += T)
        if ((adjw[k] & 0xFFFFu) == 0x3F80u) hit = 1;
    if (hit) *sh_flag = 1;
    __syncthreads();
    return (*sh_flag == 0) ? 1 : 0;
}

// ================= K1: detect + zero + x-stats + param copies ===============
// grid 192: bid<128 x-stats; bid>=128: flag/zero/copies/W-conversions.
__global__ __launch_bounds__(512) void k_prep(const void* __restrict__ adj,
        const void* __restrict__ x,
        const void* __restrict__ W_feat, const void* __restrict__ convs_W,
        const void* __restrict__ fc_g, const void* __restrict__ fc_b,
        const void* __restrict__ lin_W, const void* __restrict__ lin_b,
        const void* __restrict__ hid_g, const void* __restrict__ hid_b,
        const void* __restrict__ cls_W, const void* __restrict__ cls_b,
        const void* __restrict__ convs_b, float* ws) {
    __shared__ __align__(16) float XS[1024];
    __shared__ int sflag;
    int tid = threadIdx.x, bid = blockIdx.x;
    const int isf = detect_isf<512>((const unsigned int*)adj, tid, &sflag);
    if (bid < 128) {
        int f = tid & 127, part = tid >> 7;           // 4 parts x 32 rows
        int r0 = bid*128 + part*32;
        float s = 0.f, q = 0.f;
        for (int r = 0; r < 32; ++r) {
            float v = ldin(x, (size_t)(r0 + r)*FF + f, isf);
            s += v; q += v*v;
        }
        XS[part*128 + f] = s; XS[512 + part*128 + f] = q;
        __syncthreads();
        if (part == 0) {
            ws[OFF_XB + (size_t)bid*256 + f] =
                XS[f] + XS[128+f] + XS[256+f] + XS[384+f];
            ws[OFF_XB + (size_t)bid*256 + 128 + f] =
                XS[512+f] + XS[640+f] + XS[768+f] + XS[896+f];
        }
    } else {
        int gid = (bid - 128)*512 + tid;              // 0..32767
        if (gid < 16) ((int*)(ws + OFF_FLG))[gid] = (gid == 0) ? isf : 0;
        for (size_t i = gid; i < ZERO_SZ; i += 32768) ws[OFF_G + i] = 0.f;
        float* prm = ws + OFF_PRM;
        if (gid < 192) {
            prm[gid]       = ldin(fc_g,  gid, isf);
            prm[192 + gid] = ldin(fc_b,  gid, isf);
            prm[384 + gid] = ldin(lin_b, gid, isf);
            prm[576 + gid] = ldin(hid_g, gid, isf);
            prm[768 + gid] = ldin(hid_b, gid, isf);
        }
        if (gid < 10)   prm[960 + gid]  = ldin(cls_b, gid, isf);
        if (gid < 1920) prm[976 + gid]  = ldin(cls_W, gid, isf);
        if (gid < 576)  prm[2896 + gid] = ldin(convs_b, gid, isf);
        unsigned short* wlt = (unsigned short*)(ws + OFF_WLT);
        for (int i = gid; i < HH*HH; i += 32768)
            wlt[i] = bf16bits(ldin(lin_W, i, isf));
        // raw W^T conversions (coalesced read, scattered 2B write -> L2)
        unsigned short* wpf = (unsigned short*)(ws + OFF_WPF);
        if (gid < FF*HH) {                            // 24576
            int k = gid / HH, n = gid - k*HH;
            wpf[(size_t)n*FF + k] = bf16bits(ldin(W_feat, (size_t)k*HH + n, isf));
        }
        unsigned short* wpc = (unsigned short*)(ws + OFF_WPC);
        for (int i = gid; i < 3*HH*HH; i += 32768) {  // 110592
            int l = i / (HH*HH), r2 = i - l*HH*HH;
            int k = r2 / HH, n = r2 - k*HH;
            wpc[(size_t)l*HH*HH + (size_t)n*HH + k] =
                bf16bits(ldin(convs_W, (size_t)l*HH*HH + (size_t)k*HH + n, isf));
        }
    }
}

// ================= K2: graph build (bid<512) + gemm0 (bid>=512) =============
// Graph blocks at LOW bids: their 67 MB HBM stream starts first and overlaps
// the latency-bound gemm0 blocks. gemm0: A' = a_k*x + c_k folded in regs.
__global__ __launch_bounds__(512, 4) void k_gg0(const void* __restrict__ adj,
        const void* __restrict__ x, const void* __restrict__ gg,
        const void* __restrict__ bb, float* ws) {
    __shared__ __align__(16) float XSg[1024];
    __shared__ __align__(16) float AF[FF], CF[FF], SH2[384];
    int tid = threadIdx.x, bid = blockIdx.x;
    const int isf = rdflag(ws);
    if (bid < 512) {
        // ---------------- graph build (ballot compaction) ----------------
        int gb = bid;
        int wv = tid >> 6, lane = tid & 63;
        unsigned short* cols = (unsigned short*)(ws + OFF_COLS);
        unsigned long long lmask = (1ull << lane) - 1ull;
        #pragma unroll
        for (int rr = 0; rr < 4; ++rr) {
            int row = gb*32 + wv*4 + rr;
            int irow = row & (NN - 1);
            int base = 0;
            if (isf) {
                const unsigned int* ap = (const unsigned int*)adj + (size_t)row*NN;
                #pragma unroll
                for (int i = 0; i < 4; ++i) {
                    u32x4 v = *(const u32x4*)(ap + i*256 + lane*4);
                    #pragma unroll
                    for (int e = 0; e < 4; ++e) {
                        int j = i*256 + lane*4 + e;
                        bool hit = ((v[e] & 0x7FFFFFFFu) != 0u) || (j == irow);
                        unsigned long long mk = __ballot(hit);
                        int rk = __popcll(mk & lmask);
                        if (hit) {
                            int p = base + rk;
                            if (p < MAXC) cols[(size_t)row*MAXC + p] = (unsigned short)j;
                        }
                        base += __popcll(mk);
                    }
                }
            } else {
                const unsigned int* ap = (const unsigned int*)adj + (size_t)row*(NN/2);
                #pragma unroll
                for (int i = 0; i < 2; ++i) {
                    u32x4 v = *(const u32x4*)(ap + i*256 + lane*4);
                    #pragma unroll
                    for (int e = 0; e < 4; ++e) {
                        int wid = i*256 + lane*4 + e;
                        #pragma unroll
                        for (int h = 0; h < 2; ++h) {
                            unsigned int hv = (h == 0) ? (v[e] & 0xFFFFu) : (v[e] >> 16);
                            int j = 2*wid + h;
                            bool hit = ((hv & 0x7FFFu) != 0u) || (j == irow);
                            unsigned long long mk = __ballot(hit);
                            int rk = __popcll(mk & lmask);
                            if (hit) {
                                int p = base + rk;
                                if (p < MAXC) cols[(size_t)row*MAXC + p] = (unsigned short)j;
                            }
                            base += __popcll(mk);
                        }
                    }
                }
            }
            if (lane == 0) {
                ((int*)(ws + OFF_CNT))[row] = base > MAXC ? MAXC : base;
                ws[OFF_DIS + row] = rsqrtf((float)base);   // deg >= 1 (self loop)
            }
        }
        return;
    }
    // ---------------- gemm0 ----------------
    // stats: 4-way parallel bucket reduce (32 serial iters, not 128)
    {
        int f = tid & 127, part = tid >> 7;
        float s = 0.f, q = 0.f;
        for (int b = part; b < 128; b += 4) {
            s += ws[OFF_XB + (size_t)b*256 + f];
            q += ws[OFF_XB + (size_t)b*256 + 128 + f];
        }
        XSg[part*128 + f] = s; XSg[512 + part*128 + f] = q;
    }
    for (int i = tid; i < 384; i += 512) SH2[i] = 0.f;
    __syncthreads();
    if (tid < FF) {
        float s = XSg[tid] + XSg[128+tid] + XSg[256+tid] + XSg[384+tid];
        float q = XSg[512+tid] + XSg[640+tid] + XSg[768+tid] + XSg[896+tid];
        float mean = s*(1.f/NROWS), var = q*(1.f/NROWS) - mean*mean;
        float a = ldin(gg, tid, isf) * rsqrtf(var + EPSV);
        AF[tid] = a;
        CF[tid] = ldin(bb, tid, isf) - mean*a;
    }
    __syncthreads();
    const __hip_bfloat16* BT = (const __hip_bfloat16*)(ws + OFF_WPF);
    int lane = tid & 63, w8 = tid >> 6;
    int wr = w8 & 1, wc = w8 >> 1;
    int m = lane & 15, quad = lane >> 4;
    int t = bid - 512;
    int batch = t & 15, seg = t >> 4;
    int row0 = batch*NN + seg*32;
    int rowA = row0 + wr*16 + m;
    f32x4 acc[3];
    #pragma unroll
    for (int tt = 0; tt < 3; ++tt) acc[tt] = f32x4{0.f,0.f,0.f,0.f};
    #pragma unroll
    for (int kb = 0; kb < FF/32; ++kb) {
        int k0 = kb*32 + quad*8;
        float xv[8];
        if (isf) {
            const float* Ar = (const float*)x + (size_t)rowA*FF + k0;
            f32x4 v0 = *(const f32x4*)Ar, v1 = *(const f32x4*)(Ar + 4);
            #pragma unroll
            for (int e = 0; e < 4; ++e) { xv[e] = v0[e]; xv[4+e] = v1[e]; }
        } else {
            union { short8 s8; __hip_bfloat16 h[8]; } u;
            u.s8 = *(const short8*)((const __hip_bfloat16*)x + (size_t)rowA*FF + k0);
            #pragma unroll
            for (int e = 0; e < 8; ++e) xv[e] = __bfloat162float(u.h[e]);
        }
        union { short8 s8; __hip_bfloat16 h[8]; } ua;
        #pragma unroll
        for (int e = 0; e < 8; ++e)
            ua.h[e] = __float2bfloat16(AF[k0+e]*xv[e] + CF[k0+e]);
        short8 a = ua.s8;
        #pragma unroll
        for (int tt = 0; tt < 3; ++tt) {
            short8 b = *(const short8*)(BT + (size_t)(wc*48 + tt*16 + m)*FF + k0);
            acc[tt] = __builtin_amdgcn_mfma_f32_16x16x32_bf16(a, b, acc[tt], 0, 0, 0);
        }
    }
    __hip_bfloat16* H0 = (__hip_bfloat16*)(ws + OFF_H0);
    #pragma unroll
    for (int tt = 0; tt < 3; ++tt) {
        int nl = wc*48 + tt*16 + m;
        float s = 0.f, sq = 0.f;
        #pragma unroll
        for (int r = 0; r < 4; ++r) {
            int row = row0 + wr*16 + quad*4 + r;
            float o = fmaxf(acc[tt][r], 0.f);         // c-term is inside A'@W
            H0[(size_t)row*HH + nl] = __float2bfloat16(o);
            s += o; sq += o*o;
        }
        s  += __shfl_xor(s, 16, 64);  s  += __shfl_xor(s, 32, 64);
        sq += __shfl_xor(sq, 16, 64); sq += __shfl_xor(sq, 32, 64);
        if (quad == 0) {
            atomicAdd(&SH2[nl], s);
            atomicAdd(&SH2[192 + nl], sq);
        }
    }
    __syncthreads();
    float* st = ws + OFF_SH + (size_t)(t & 7)*512;
    if (tid < 192) {
        atomicAdd(&st[tid], SH2[tid]);
        atomicAdd(&st[256 + tid], SH2[192 + tid]);
    }
}

// ================= K per-layer: conv gemm with A-side BN fold ===============
__global__ __launch_bounds__(512, 4) void k_gemmc(const void* __restrict__ gg,
        const void* __restrict__ bb, int layer, float* __restrict__ ws) {
    __shared__ __align__(16) float AF[HH], CF[HH];
    __shared__ __align__(16) unsigned short ZT[32*HH];   // 12 KB
    int tid = threadIdx.x, bid = blockIdx.x;
    const int isf = rdflag(ws);
    if (tid < HH) {
        const float* st = ws + OFF_SH + (size_t)layer*4096;
        float s = 0.f, q = 0.f;
        #pragma unroll
        for (int b = 0; b < 8; ++b) {
            s += st[b*512 + tid];
            q += st[b*512 + 256 + tid];
        }
        float mean = s*(1.f/NROWS), var = q*(1.f/NROWS) - mean*mean;
        float a = ldin(gg, (size_t)layer*HH + tid, isf) * rsqrtf(var + EPSV);
        AF[tid] = a;
        CF[tid] = ldin(bb, (size_t)layer*HH + tid, isf) - mean*a;
    }
    __syncthreads();
    const __hip_bfloat16* BT = (const __hip_bfloat16*)(ws + OFF_WPC) +
                               (size_t)layer*HH*HH;
    int lane = tid & 63, w8 = tid >> 6;
    int wr = w8 & 1, wc = w8 >> 1;
    int m = lane & 15, quad = lane >> 4;
    int batch = bid & 15, seg = bid >> 4;
    int row0 = batch*NN + seg*32;
    int rowA = row0 + wr*16 + m;
    const __hip_bfloat16* A = (const __hip_bfloat16*)(ws + OFF_H0);
    f32x4 acc[3];
    #pragma unroll
    for (int tt = 0; tt < 3; ++tt) acc[tt] = f32x4{0.f,0.f,0.f,0.f};
    #pragma unroll
    for (int kb = 0; kb < HH/32; ++kb) {
        int k0 = kb*32 + quad*8;
        union { short8 s8; __hip_bfloat16 h[8]; } u;
        u.s8 = *(const short8*)(A + (size_t)rowA*HH + k0);
        union { short8 s8; __hip_bfloat16 h[8]; } ua;
        #pragma unroll
        for (int e = 0; e < 8; ++e)
            ua.h[e] = __float2bfloat16(AF[k0+e]*__bfloat162float(u.h[e]) + CF[k0+e]);
        short8 a = ua.s8;
        #pragma unroll
        for (int tt = 0; tt < 3; ++tt) {
            short8 b = *(const short8*)(BT + (size_t)(wc*48 + tt*16 + m)*HH + k0);
            acc[tt] = __builtin_amdgcn_mfma_f32_16x16x32_bf16(a, b, acc[tt], 0, 0, 0);
        }
    }
    const float* dis = ws + OFF_DIS;
    float sc[4];
    #pragma unroll
    for (int r = 0; r < 4; ++r) sc[r] = dis[row0 + wr*16 + quad*4 + r];
    #pragma unroll
    for (int tt = 0; tt < 3; ++tt) {
        int nl = wc*48 + tt*16 + m;
        #pragma unroll
        for (int r = 0; r < 4; ++r)
            ZT[(wr*16 + quad*4 + r)*HH + nl] = bf16bits(acc[tt][r]*sc[r]);
    }
    __syncthreads();
    unsigned int* Zg = (unsigned int*)(ws + OFF_ZB) + (size_t)row0*96;
    const unsigned int* ZTu = (const unsigned int*)ZT;
    #pragma unroll
    for (int ii = 0; ii < 3; ++ii) {
        int i = tid + ii*512;
        *(u32x2*)(&Zg[2*i]) = *(const u32x2*)(&ZTu[2*i]);
    }
}

// ================= tail (256-thread version; runs in last spmm block) =======
static __device__ void tail256(char* TL, int tid, int isf, void* out,
                               const float* ws) {
    float* G1  = (float*)TL;              // [16][192]
    float* G2  = (float*)(TL + 12288);    // [16][192]
    float* LG  = (float*)(TL + 24576);    // [16][10]
    float* LSE = (float*)(TL + 25216);    // [16]
    const float* prm = ws + OFF_PRM;
    const float* g = ws + OFF_G;
    if (tid < HH) {
        float s = 0.f, sq = 0.f;
        for (int b = 0; b < BB; ++b) {
            float v = g[b*HH + tid]*(1.f/NN);
            s += v; sq += v*v;
        }
        float mean = s*(1.f/BB), var = sq*(1.f/BB) - mean*mean;
        float a = prm[tid] * rsqrtf(var + EPSV);
        float c = prm[192 + tid] - mean*a;
        for (int b = 0; b < BB; ++b) G1[b*HH + tid] = g[b*HH + tid]*(1.f/NN)*a + c;
    }
    __syncthreads();
    const unsigned short* Wlt = (const unsigned short*)(ws + OFF_WLT);
    #pragma unroll
    for (int pass = 0; pass < 2; ++pass) {
        int t2 = tid + pass*256;
        int b = t2 >> 5, grp = t2 & 31, n0 = grp*6;
        float acc[6];
        #pragma unroll
        for (int e = 0; e < 6; ++e) acc[e] = prm[384 + n0 + e];
        for (int k = 0; k < HH; ++k) {
            float gv = G1[b*HH + k];
            const unsigned int* wp = (const unsigned int*)(Wlt + (size_t)k*HH + n0);
            unsigned int w0 = wp[0], w1 = wp[1], w2 = wp[2];
            acc[0] += gv*blo(w0); acc[1] += gv*bhi(w0);
            acc[2] += gv*blo(w1); acc[3] += gv*bhi(w1);
            acc[4] += gv*blo(w2); acc[5] += gv*bhi(w2);
        }
        #pragma unroll
        for (int e = 0; e < 6; ++e) G2[b*HH + n0 + e] = fmaxf(acc[e], 0.f);
    }
    __syncthreads();
    if (tid < HH) {
        float s = 0.f, sq = 0.f;
        for (int bb = 0; bb < BB; ++bb) { float v = G2[bb*HH + tid]; s += v; sq += v*v; }
        float mean = s*(1.f/BB), var = sq*(1.f/BB) - mean*mean;
        float a = prm[576 + tid] * rsqrtf(var + EPSV);
        float c = prm[768 + tid] - mean*a;
        for (int bb = 0; bb < BB; ++bb) G2[bb*HH + tid] = G2[bb*HH + tid]*a + c;
    }
    __syncthreads();
    if (tid < BB*10) {
        int bb = tid/10, kk = tid%10;
        float a2 = prm[960 + kk];
        for (int h = 0; h < HH; ++h) a2 += G2[bb*HH + h]*prm[976 + h*10 + kk];
        LG[bb*10 + kk] = a2;
    }
    __syncthreads();
    if (tid < BB) {
        float mx = -1e30f;
        for (int k = 0; k < 10; ++k) mx = fmaxf(mx, LG[tid*10 + k]);
        float s = 0.f;
        for (int k = 0; k < 10; ++k) s += expf(LG[tid*10 + k] - mx);
        LSE[tid] = mx + logf(s);
    }
    __syncthreads();
    if (tid < BB*10) {
        int bb = tid/10;
        float v = LG[bb*10 + tid%10] - LSE[bb];
        if (isf) ((float*)out)[tid] = v;
        else     ((__hip_bfloat16*)out)[tid] = __float2bfloat16(v);
    }
}

// ================= K per-layer: spmm direct-from-L2 (+tail on layer 2) ======
__global__ __launch_bounds__(256, 6) void k_spmm(int layer, void* __restrict__ out,
                                                 float* __restrict__ ws) {
    __shared__ float SH[64];
    __shared__ __align__(16) char TL[25280];
    __shared__ int lastflag;
    int tid = threadIdx.x, bid = blockIdx.x;
    const int isf = rdflag(ws);
    for (int i = tid; i < 64; i += 256) SH[i] = 0.f;
    int batch = bid / 192, rem = bid - batch*192;
    int slice = rem >> 5, rg = rem & 31;
    int u = tid >> 3, d = tid & 7;
    int row = batch*NN + rg*32 + u;
    int c0 = slice*32;
    int base = slice*16 + d*2;
    const int c = ((const int*)(ws + OFF_CNT))[row];
    const unsigned short* cl = (const unsigned short*)(ws + OFF_COLS) + (size_t)row*MAXC;
    const unsigned int* Zb = (const unsigned int*)(ws + OFF_ZB) + (size_t)batch*NN*96;
    float bch[4];
    #pragma unroll
    for (int e = 0; e < 4; ++e)
        bch[e] = ws[OFF_PRM + 2896 + (size_t)layer*HH + c0 + d*4 + e];
    float a0=0.f, a1=0.f, a2=0.f, a3=0.f;
    int k = 0;
    for (; k + 8 <= c; k += 8) {
        u32x4 cw = *(const u32x4*)(cl + k);
        int j[8];
        j[0]=(int)(cw[0]&0xFFFFu); j[1]=(int)(cw[0]>>16);
        j[2]=(int)(cw[1]&0xFFFFu); j[3]=(int)(cw[1]>>16);
        j[4]=(int)(cw[2]&0xFFFFu); j[5]=(int)(cw[2]>>16);
        j[6]=(int)(cw[3]&0xFFFFu); j[7]=(int)(cw[3]>>16);
        u32x2 z[8];
        #pragma unroll
        for (int e = 0; e < 8; ++e)
            z[e] = *(const u32x2*)(&Zb[(size_t)j[e]*96 + base]);
        #pragma unroll
        for (int e = 0; e < 8; ++e) {
            a0 += blo(z[e][0]); a1 += bhi(z[e][0]);
            a2 += blo(z[e][1]); a3 += bhi(z[e][1]);
        }
    }
    for (; k < c; ++k) {
        u32x2 z = *(const u32x2*)(&Zb[(size_t)cl[k]*96 + base]);
        a0 += blo(z[0]); a1 += bhi(z[0]);
        a2 += blo(z[1]); a3 += bhi(z[1]);
    }
    float dd = ws[OFF_DIS + row];
    float o0 = fmaxf(dd*a0 + bch[0], 0.f);
    float o1 = fmaxf(dd*a1 + bch[1], 0.f);
    float o2 = fmaxf(dd*a2 + bch[2], 0.f);
    float o3 = fmaxf(dd*a3 + bch[3], 0.f);
    unsigned int* H0u = (unsigned int*)(ws + OFF_H0);
    u32x2 outw; outw[0] = packbf(o0,o1); outw[1] = packbf(o2,o3);
    *(u32x2*)(&H0u[(size_t)row*96 + base]) = outw;
    float s_acc[4] = {o0,o1,o2,o3};
    float q_acc[4] = {o0*o0,o1*o1,o2*o2,o3*o3};
    const int is_pool = (layer == 2);
    #pragma unroll
    for (int e = 0; e < 4; ++e) {
        #pragma unroll
        for (int mask = 8; mask < 64; mask <<= 1) {
            s_acc[e] += __shfl_xor(s_acc[e], mask, 64);
            if (!is_pool) q_acc[e] += __shfl_xor(q_acc[e], mask, 64);
        }
    }
    __syncthreads();
    if ((tid & 63) < 8) {
        #pragma unroll
        for (int e = 0; e < 4; ++e) {
            atomicAdd(&SH[d*4 + e], s_acc[e]);
            if (!is_pool) atomicAdd(&SH[32 + d*4 + e], q_acc[e]);
        }
    }
    __syncthreads();
    if (tid < 32) {
        if (is_pool) {
            atomicAdd(&ws[OFF_G + (size_t)batch*HH + c0 + tid], SH[tid]);
        } else {
            float* st = ws + OFF_SH + (size_t)(layer + 1)*4096 + (size_t)(bid & 7)*512;
            atomicAdd(&st[c0 + tid],       SH[tid]);
            atomicAdd(&st[256 + c0 + tid], SH[32 + tid]);
        }
    }
    if (layer == 2) {
        // all pool atomics of this block drained by the syncthreads' vmcnt(0)
        __syncthreads();
        if (tid == 0) {
            int* cnt2 = (int*)(ws + OFF_FLG) + 1;
            int old = __hip_atomic_fetch_add(cnt2, 1, __ATOMIC_ACQ_REL,
                                             __HIP_MEMORY_SCOPE_AGENT);
            lastflag = (old == 3071) ? 1 : 0;
        }
        __syncthreads();
        if (lastflag) tail256(TL, tid, isf, out, ws);
    }
}

extern "C" void kernel_launch(void* const* d_in, const int* in_sizes, int n_in,
                              void* d_out, int out_size, void* d_ws, size_t ws_size,
                              hipStream_t stream) {
    const void* x       = d_in[0];
    const void* adj     = d_in[1];
    const void* bnf_g   = d_in[2];
    const void* bnf_b   = d_in[3];
    const void* W_feat  = d_in[4];
    const void* bnc_g   = d_in[5];
    const void* bnc_b   = d_in[6];
    const void* convs_W = d_in[7];
    const void* convs_b = d_in[8];
    const void* fc_g    = d_in[9];
    const void* fc_b    = d_in[10];
    const void* lin_W   = d_in[11];
    const void* lin_b   = d_in[12];
    const void* hid_g   = d_in[13];
    const void* hid_b   = d_in[14];
    const void* cls_W   = d_in[15];
    const void* cls_b   = d_in[16];
    float* ws = (float*)d_ws;

    k_prep<<<192, 512, 0, stream>>>(adj, x, W_feat, convs_W, fc_g, fc_b,
                                    lin_W, lin_b, hid_g, hid_b, cls_W, cls_b,
                                    convs_b, ws);
    k_gg0<<<1024, 512, 0, stream>>>(adj, x, bnf_g, bnf_b, ws);
    for (int l = 0; l < 3; ++l) {
        k_gemmc<<<512, 512, 0, stream>>>(bnc_g, bnc_b, l, ws);
        k_spmm<<<3072, 256, 0, stream>>>(l, d_out, ws);
    }
}

// Round 11
// 297.255 us; speedup vs baseline: 1.2968x; 1.2968x over previous
//
#include <hip/hip_runtime.h>
#include <hip/hip_bf16.h>

#define BB 16
#define NN 1024
#define FF 128
#define HH 192
#define NROWS (BB*NN)
#define MAXC 128
#define EPSV 1e-5f

// ---------------- workspace layout (float units) ----------------
constexpr size_t OFF_H0  = 0;                                 // [NROWS*HH] bf16
constexpr size_t OFF_ZB  = OFF_H0 + (size_t)NROWS*HH/2;       // [NROWS*HH] bf16
constexpr size_t OFF_DIS = OFF_ZB + (size_t)NROWS*HH/2;       // [NROWS] f32
constexpr size_t OFF_G   = OFF_DIS + NROWS;                   // [BB*HH] pool sums
constexpr size_t OFF_SH  = OFF_G + BB*HH;                     // 3 stages x 8 buckets x 512
constexpr size_t SH_SIZE = 3*8*512;
constexpr size_t ZERO_SZ = BB*HH + SH_SIZE;                   // zeroed in k_prep
constexpr size_t OFF_FLG = OFF_SH + SH_SIZE;                  // [0] isf flag
constexpr size_t OFF_PRM = OFF_FLG + 16;                      // f32 params [3584]
// prm: 0 fc_g,192 fc_b,384 lin_b,576 hid_g,768 hid_b,960 cls_b(10),
//      976 cls_W(1920), 2896 convs_b(576)
constexpr size_t OFF_WLT = OFF_PRM + 3584;                    // lin_W bf16 [HH*HH]
constexpr size_t OFF_XB  = OFF_WLT + (size_t)HH*HH/2;         // x-stat buckets [128][256]
constexpr size_t OFF_WPF = OFF_XB + 128*256;                  // RAW W_feat^T bf16 [192][128]
constexpr size_t OFF_WPC = OFF_WPF + (size_t)HH*FF/2;         // RAW convs_W^T bf16 [3][192][192]
constexpr size_t OFF_CNT = OFF_WPC + 3*(size_t)HH*HH/2;       // [NROWS] int32
constexpr size_t OFF_COLS= OFF_CNT + NROWS;                   // [NROWS*MAXC] u16

typedef __attribute__((ext_vector_type(8))) short short8;
typedef __attribute__((ext_vector_type(4))) float f32x4;
typedef __attribute__((ext_vector_type(4))) unsigned int u32x4;
typedef __attribute__((ext_vector_type(2))) unsigned int u32x2;

static __device__ __forceinline__ float ldin(const void* p, size_t i, int isf) {
    return isf ? ((const float*)p)[i]
               : __bfloat162float(((const __hip_bfloat16*)p)[i]);
}
static __device__ __forceinline__ float blo(unsigned int u) {
    union { unsigned int x; float f; } v; v.x = u << 16; return v.f;
}
static __device__ __forceinline__ float bhi(unsigned int u) {
    union { unsigned int x; float f; } v; v.x = u & 0xFFFF0000u; return v.f;
}
static __device__ __forceinline__ unsigned int packbf(float a, float b) {
    union { unsigned int u; __hip_bfloat16 h[2]; } p;
    p.h[0] = __float2bfloat16(a); p.h[1] = __float2bfloat16(b);
    return p.u;
}
static __device__ __forceinline__ unsigned short bf16bits(float a) {
    union { unsigned short u; __hip_bfloat16 h; } p;
    p.h = __float2bfloat16(a); return p.u;
}
static __device__ __forceinline__ int rdflag(const float* ws) {
    return ((const int*)(ws + OFF_FLG))[0];
}

// dtype self-detection — run ONLY inside k_prep; published to ws flag.
template<int T>
static __device__ __forceinline__ int detect_isf(const unsigned int* __restrict__ adjw,
                                                 int tid, int* sh_flag) {
    if (tid == 0) *sh_flag = 0;
    __syncthreads();
    int hit = 0;
    for (int k = tid; k < 1024; k += T)
        if ((adjw[k] & 0xFFFFu) == 0x3F80u) hit = 1;
    if (hit) *sh_flag = 1;
    __syncthreads();
    return (*sh_flag == 0) ? 1 : 0;
}

// ================= K1: detect + zero + x-stats + param copies ===============
// grid 192: bid<128 x-stats; bid>=128: flag/zero/copies/W-conversions.
__global__ __launch_bounds__(512) void k_prep(const void* __restrict__ adj,
        const void* __restrict__ x,
        const void* __restrict__ W_feat, const void* __restrict__ convs_W,
        const void* __restrict__ fc_g, const void* __restrict__ fc_b,
        const void* __restrict__ lin_W, const void* __restrict__ lin_b,
        const void* __restrict__ hid_g, const void* __restrict__ hid_b,
        const void* __restrict__ cls_W, const void* __restrict__ cls_b,
        const void* __restrict__ convs_b, float* ws) {
    __shared__ __align__(16) float XS[1024];
    __shared__ int sflag;
    int tid = threadIdx.x, bid = blockIdx.x;
    const int isf = detect_isf<512>((const unsigned int*)adj, tid, &sflag);
    if (bid < 128) {
        int f = tid & 127, part = tid >> 7;           // 4 parts x 32 rows
        int r0 = bid*128 + part*32;
        float s = 0.f, q = 0.f;
        for (int r = 0; r < 32; ++r) {
            float v = ldin(x, (size_t)(r0 + r)*FF + f, isf);
            s += v; q += v*v;
        }
        XS[part*128 + f] = s; XS[512 + part*128 + f] = q;
        __syncthreads();
        if (part == 0) {
            ws[OFF_XB + (size_t)bid*256 + f] =
                XS[f] + XS[128+f] + XS[256+f] + XS[384+f];
            ws[OFF_XB + (size_t)bid*256 + 128 + f] =
                XS[512+f] + XS[640+f] + XS[768+f] + XS[896+f];
        }
    } else {
        int gid = (bid - 128)*512 + tid;              // 0..32767
        if (gid < 16) ((int*)(ws + OFF_FLG))[gid] = (gid == 0) ? isf : 0;
        for (size_t i = gid; i < ZERO_SZ; i += 32768) ws[OFF_G + i] = 0.f;
        float* prm = ws + OFF_PRM;
        if (gid < 192) {
            prm[gid]       = ldin(fc_g,  gid, isf);
            prm[192 + gid] = ldin(fc_b,  gid, isf);
            prm[384 + gid] = ldin(lin_b, gid, isf);
            prm[576 + gid] = ldin(hid_g, gid, isf);
            prm[768 + gid] = ldin(hid_b, gid, isf);
        }
        if (gid < 10)   prm[960 + gid]  = ldin(cls_b, gid, isf);
        if (gid < 1920) prm[976 + gid]  = ldin(cls_W, gid, isf);
        if (gid < 576)  prm[2896 + gid] = ldin(convs_b, gid, isf);
        unsigned short* wlt = (unsigned short*)(ws + OFF_WLT);
        for (int i = gid; i < HH*HH; i += 32768)
            wlt[i] = bf16bits(ldin(lin_W, i, isf));
        // raw W^T conversions (coalesced read, scattered 2B write -> L2)
        unsigned short* wpf = (unsigned short*)(ws + OFF_WPF);
        if (gid < FF*HH) {                            // 24576
            int k = gid / HH, n = gid - k*HH;
            wpf[(size_t)n*FF + k] = bf16bits(ldin(W_feat, (size_t)k*HH + n, isf));
        }
        unsigned short* wpc = (unsigned short*)(ws + OFF_WPC);
        for (int i = gid; i < 3*HH*HH; i += 32768) {  // 110592
            int l = i / (HH*HH), r2 = i - l*HH*HH;
            int k = r2 / HH, n = r2 - k*HH;
            wpc[(size_t)l*HH*HH + (size_t)n*HH + k] =
                bf16bits(ldin(convs_W, (size_t)l*HH*HH + (size_t)k*HH + n, isf));
        }
    }
}

// ================= K2: graph build (bid<512) + gemm0 (bid>=512) =============
// Graph blocks at LOW bids: their 67 MB HBM stream starts first and overlaps
// the latency-bound gemm0 blocks. gemm0: A' = a_k*x + c_k folded in regs.
__global__ __launch_bounds__(512, 4) void k_gg0(const void* __restrict__ adj,
        const void* __restrict__ x, const void* __restrict__ gg,
        const void* __restrict__ bb, float* ws) {
    __shared__ __align__(16) float XSg[1024];
    __shared__ __align__(16) float AF[FF], CF[FF], SH2[384];
    int tid = threadIdx.x, bid = blockIdx.x;
    const int isf = rdflag(ws);
    if (bid < 512) {
        // ---------------- graph build (ballot compaction) ----------------
        int gb = bid;
        int wv = tid >> 6, lane = tid & 63;
        unsigned short* cols = (unsigned short*)(ws + OFF_COLS);
        unsigned long long lmask = (1ull << lane) - 1ull;
        #pragma unroll
        for (int rr = 0; rr < 4; ++rr) {
            int row = gb*32 + wv*4 + rr;
            int irow = row & (NN - 1);
            int base = 0;
            if (isf) {
                const unsigned int* ap = (const unsigned int*)adj + (size_t)row*NN;
                #pragma unroll
                for (int i = 0; i < 4; ++i) {
                    u32x4 v = *(const u32x4*)(ap + i*256 + lane*4);
                    #pragma unroll
                    for (int e = 0; e < 4; ++e) {
                        int j = i*256 + lane*4 + e;
                        bool hit = ((v[e] & 0x7FFFFFFFu) != 0u) || (j == irow);
                        unsigned long long mk = __ballot(hit);
                        int rk = __popcll(mk & lmask);
                        if (hit) {
                            int p = base + rk;
                            if (p < MAXC) cols[(size_t)row*MAXC + p] = (unsigned short)j;
                        }
                        base += __popcll(mk);
                    }
                }
            } else {
                const unsigned int* ap = (const unsigned int*)adj + (size_t)row*(NN/2);
                #pragma unroll
                for (int i = 0; i < 2; ++i) {
                    u32x4 v = *(const u32x4*)(ap + i*256 + lane*4);
                    #pragma unroll
                    for (int e = 0; e < 4; ++e) {
                        int wid = i*256 + lane*4 + e;
                        #pragma unroll
                        for (int h = 0; h < 2; ++h) {
                            unsigned int hv = (h == 0) ? (v[e] & 0xFFFFu) : (v[e] >> 16);
                            int j = 2*wid + h;
                            bool hit = ((hv & 0x7FFFu) != 0u) || (j == irow);
                            unsigned long long mk = __ballot(hit);
                            int rk = __popcll(mk & lmask);
                            if (hit) {
                                int p = base + rk;
                                if (p < MAXC) cols[(size_t)row*MAXC + p] = (unsigned short)j;
                            }
                            base += __popcll(mk);
                        }
                    }
                }
            }
            if (lane == 0) {
                ((int*)(ws + OFF_CNT))[row] = base > MAXC ? MAXC : base;
                ws[OFF_DIS + row] = rsqrtf((float)base);   // deg >= 1 (self loop)
            }
        }
        return;
    }
    // ---------------- gemm0 ----------------
    // stats: 4-way parallel bucket reduce (32 serial iters, not 128)
    {
        int f = tid & 127, part = tid >> 7;
        float s = 0.f, q = 0.f;
        for (int b = part; b < 128; b += 4) {
            s += ws[OFF_XB + (size_t)b*256 + f];
            q += ws[OFF_XB + (size_t)b*256 + 128 + f];
        }
        XSg[part*128 + f] = s; XSg[512 + part*128 + f] = q;
    }
    for (int i = tid; i < 384; i += 512) SH2[i] = 0.f;
    __syncthreads();
    if (tid < FF) {
        float s = XSg[tid] + XSg[128+tid] + XSg[256+tid] + XSg[384+tid];
        float q = XSg[512+tid] + XSg[640+tid] + XSg[768+tid] + XSg[896+tid];
        float mean = s*(1.f/NROWS), var = q*(1.f/NROWS) - mean*mean;
        float a = ldin(gg, tid, isf) * rsqrtf(var + EPSV);
        AF[tid] = a;
        CF[tid] = ldin(bb, tid, isf) - mean*a;
    }
    __syncthreads();
    const __hip_bfloat16* BT = (const __hip_bfloat16*)(ws + OFF_WPF);
    int lane = tid & 63, w8 = tid >> 6;
    int wr = w8 & 1, wc = w8 >> 1;
    int m = lane & 15, quad = lane >> 4;
    int t = bid - 512;
    int batch = t & 15, seg = t >> 4;
    int row0 = batch*NN + seg*32;
    int rowA = row0 + wr*16 + m;
    f32x4 acc[3];
    #pragma unroll
    for (int tt = 0; tt < 3; ++tt) acc[tt] = f32x4{0.f,0.f,0.f,0.f};
    #pragma unroll
    for (int kb = 0; kb < FF/32; ++kb) {
        int k0 = kb*32 + quad*8;
        float xv[8];
        if (isf) {
            const float* Ar = (const float*)x + (size_t)rowA*FF + k0;
            f32x4 v0 = *(const f32x4*)Ar, v1 = *(const f32x4*)(Ar + 4);
            #pragma unroll
            for (int e = 0; e < 4; ++e) { xv[e] = v0[e]; xv[4+e] = v1[e]; }
        } else {
            union { short8 s8; __hip_bfloat16 h[8]; } u;
            u.s8 = *(const short8*)((const __hip_bfloat16*)x + (size_t)rowA*FF + k0);
            #pragma unroll
            for (int e = 0; e < 8; ++e) xv[e] = __bfloat162float(u.h[e]);
        }
        union { short8 s8; __hip_bfloat16 h[8]; } ua;
        #pragma unroll
        for (int e = 0; e < 8; ++e)
            ua.h[e] = __float2bfloat16(AF[k0+e]*xv[e] + CF[k0+e]);
        short8 a = ua.s8;
        #pragma unroll
        for (int tt = 0; tt < 3; ++tt) {
            short8 b = *(const short8*)(BT + (size_t)(wc*48 + tt*16 + m)*FF + k0);
            acc[tt] = __builtin_amdgcn_mfma_f32_16x16x32_bf16(a, b, acc[tt], 0, 0, 0);
        }
    }
    __hip_bfloat16* H0 = (__hip_bfloat16*)(ws + OFF_H0);
    #pragma unroll
    for (int tt = 0; tt < 3; ++tt) {
        int nl = wc*48 + tt*16 + m;
        float s = 0.f, sq = 0.f;
        #pragma unroll
        for (int r = 0; r < 4; ++r) {
            int row = row0 + wr*16 + quad*4 + r;
            float o = fmaxf(acc[tt][r], 0.f);         // c-term is inside A'@W
            H0[(size_t)row*HH + nl] = __float2bfloat16(o);
            s += o; sq += o*o;
        }
        s  += __shfl_xor(s, 16, 64);  s  += __shfl_xor(s, 32, 64);
        sq += __shfl_xor(sq, 16, 64); sq += __shfl_xor(sq, 32, 64);
        if (quad == 0) {
            atomicAdd(&SH2[nl], s);
            atomicAdd(&SH2[192 + nl], sq);
        }
    }
    __syncthreads();
    float* st = ws + OFF_SH + (size_t)(t & 7)*512;
    if (tid < 192) {
        atomicAdd(&st[tid], SH2[tid]);
        atomicAdd(&st[256 + tid], SH2[192 + tid]);
    }
}

// ================= K per-layer: conv gemm with A-side BN fold ===============
__global__ __launch_bounds__(512, 4) void k_gemmc(const void* __restrict__ gg,
        const void* __restrict__ bb, int layer, float* __restrict__ ws) {
    __shared__ __align__(16) float AF[HH], CF[HH];
    __shared__ __align__(16) unsigned short ZT[32*HH];   // 12 KB
    int tid = threadIdx.x, bid = blockIdx.x;
    const int isf = rdflag(ws);
    if (tid < HH) {
        const float* st = ws + OFF_SH + (size_t)layer*4096;
        float s = 0.f, q = 0.f;
        #pragma unroll
        for (int b = 0; b < 8; ++b) {
            s += st[b*512 + tid];
            q += st[b*512 + 256 + tid];
        }
        float mean = s*(1.f/NROWS), var = q*(1.f/NROWS) - mean*mean;
        float a = ldin(gg, (size_t)layer*HH + tid, isf) * rsqrtf(var + EPSV);
        AF[tid] = a;
        CF[tid] = ldin(bb, (size_t)layer*HH + tid, isf) - mean*a;
    }
    __syncthreads();
    const __hip_bfloat16* BT = (const __hip_bfloat16*)(ws + OFF_WPC) +
                               (size_t)layer*HH*HH;
    int lane = tid & 63, w8 = tid >> 6;
    int wr = w8 & 1, wc = w8 >> 1;
    int m = lane & 15, quad = lane >> 4;
    int batch = bid & 15, seg = bid >> 4;
    int row0 = batch*NN + seg*32;
    int rowA = row0 + wr*16 + m;
    const __hip_bfloat16* A = (const __hip_bfloat16*)(ws + OFF_H0);
    f32x4 acc[3];
    #pragma unroll
    for (int tt = 0; tt < 3; ++tt) acc[tt] = f32x4{0.f,0.f,0.f,0.f};
    #pragma unroll
    for (int kb = 0; kb < HH/32; ++kb) {
        int k0 = kb*32 + quad*8;
        union { short8 s8; __hip_bfloat16 h[8]; } u;
        u.s8 = *(const short8*)(A + (size_t)rowA*HH + k0);
        union { short8 s8; __hip_bfloat16 h[8]; } ua;
        #pragma unroll
        for (int e = 0; e < 8; ++e)
            ua.h[e] = __float2bfloat16(AF[k0+e]*__bfloat162float(u.h[e]) + CF[k0+e]);
        short8 a = ua.s8;
        #pragma unroll
        for (int tt = 0; tt < 3; ++tt) {
            short8 b = *(const short8*)(BT + (size_t)(wc*48 + tt*16 + m)*HH + k0);
            acc[tt] = __builtin_amdgcn_mfma_f32_16x16x32_bf16(a, b, acc[tt], 0, 0, 0);
        }
    }
    const float* dis = ws + OFF_DIS;
    float sc[4];
    #pragma unroll
    for (int r = 0; r < 4; ++r) sc[r] = dis[row0 + wr*16 + quad*4 + r];
    #pragma unroll
    for (int tt = 0; tt < 3; ++tt) {
        int nl = wc*48 + tt*16 + m;
        #pragma unroll
        for (int r = 0; r < 4; ++r)
            ZT[(wr*16 + quad*4 + r)*HH + nl] = bf16bits(acc[tt][r]*sc[r]);
    }
    __syncthreads();
    unsigned int* Zg = (unsigned int*)(ws + OFF_ZB) + (size_t)row0*96;
    const unsigned int* ZTu = (const unsigned int*)ZT;
    #pragma unroll
    for (int ii = 0; ii < 3; ++ii) {
        int i = tid + ii*512;
        *(u32x2*)(&Zg[2*i]) = *(const u32x2*)(&ZTu[2*i]);
    }
}

// ================= K per-layer: spmm direct-from-L2 =========================
__global__ __launch_bounds__(256, 6) void k_spmm(int layer, float* __restrict__ ws) {
    __shared__ float SH[64];
    int tid = threadIdx.x, bid = blockIdx.x;
    for (int i = tid; i < 64; i += 256) SH[i] = 0.f;
    int batch = bid / 192, rem = bid - batch*192;
    int slice = rem >> 5, rg = rem & 31;
    int u = tid >> 3, d = tid & 7;
    int row = batch*NN + rg*32 + u;
    int c0 = slice*32;
    int base = slice*16 + d*2;
    const int c = ((const int*)(ws + OFF_CNT))[row];
    const unsigned short* cl = (const unsigned short*)(ws + OFF_COLS) + (size_t)row*MAXC;
    const unsigned int* Zb = (const unsigned int*)(ws + OFF_ZB) + (size_t)batch*NN*96;
    float bch[4];
    #pragma unroll
    for (int e = 0; e < 4; ++e)
        bch[e] = ws[OFF_PRM + 2896 + (size_t)layer*HH + c0 + d*4 + e];
    float a0=0.f, a1=0.f, a2=0.f, a3=0.f;
    int k = 0;
    for (; k + 8 <= c; k += 8) {
        u32x4 cw = *(const u32x4*)(cl + k);
        int j[8];
        j[0]=(int)(cw[0]&0xFFFFu); j[1]=(int)(cw[0]>>16);
        j[2]=(int)(cw[1]&0xFFFFu); j[3]=(int)(cw[1]>>16);
        j[4]=(int)(cw[2]&0xFFFFu); j[5]=(int)(cw[2]>>16);
        j[6]=(int)(cw[3]&0xFFFFu); j[7]=(int)(cw[3]>>16);
        u32x2 z[8];
        #pragma unroll
        for (int e = 0; e < 8; ++e)
            z[e] = *(const u32x2*)(&Zb[(size_t)j[e]*96 + base]);
        #pragma unroll
        for (int e = 0; e < 8; ++e) {
            a0 += blo(z[e][0]); a1 += bhi(z[e][0]);
            a2 += blo(z[e][1]); a3 += bhi(z[e][1]);
        }
    }
    for (; k < c; ++k) {
        u32x2 z = *(const u32x2*)(&Zb[(size_t)cl[k]*96 + base]);
        a0 += blo(z[0]); a1 += bhi(z[0]);
        a2 += blo(z[1]); a3 += bhi(z[1]);
    }
    float dd = ws[OFF_DIS + row];
    float o0 = fmaxf(dd*a0 + bch[0], 0.f);
    float o1 = fmaxf(dd*a1 + bch[1], 0.f);
    float o2 = fmaxf(dd*a2 + bch[2], 0.f);
    float o3 = fmaxf(dd*a3 + bch[3], 0.f);
    unsigned int* H0u = (unsigned int*)(ws + OFF_H0);
    u32x2 outw; outw[0] = packbf(o0,o1); outw[1] = packbf(o2,o3);
    *(u32x2*)(&H0u[(size_t)row*96 + base]) = outw;
    float s_acc[4] = {o0,o1,o2,o3};
    float q_acc[4] = {o0*o0,o1*o1,o2*o2,o3*o3};
    const int is_pool = (layer == 2);
    #pragma unroll
    for (int e = 0; e < 4; ++e) {
        #pragma unroll
        for (int mask = 8; mask < 64; mask <<= 1) {
            s_acc[e] += __shfl_xor(s_acc[e], mask, 64);
            if (!is_pool) q_acc[e] += __shfl_xor(q_acc[e], mask, 64);
        }
    }
    __syncthreads();
    if ((tid & 63) < 8) {
        #pragma unroll
        for (int e = 0; e < 4; ++e) {
            atomicAdd(&SH[d*4 + e], s_acc[e]);
            if (!is_pool) atomicAdd(&SH[32 + d*4 + e], q_acc[e]);
        }
    }
    __syncthreads();
    if (tid < 32) {
        if (is_pool) {
            atomicAdd(&ws[OFF_G + (size_t)batch*HH + c0 + tid], SH[tid]);
        } else {
            float* st = ws + OFF_SH + (size_t)(layer + 1)*4096 + (size_t)(bid & 7)*512;
            atomicAdd(&st[c0 + tid],       SH[tid]);
            atomicAdd(&st[256 + c0 + tid], SH[32 + tid]);
        }
    }
}

// ================= tail (separate launch; params from ws) ===================
__global__ __launch_bounds__(512) void k_tail(void* __restrict__ out,
                                              const float* __restrict__ ws) {
    __shared__ __align__(16) char SM_[62144];
    int tid = threadIdx.x;
    const int isf = rdflag(ws);
    const float* prm = ws + OFF_PRM;
    __hip_bfloat16* Wl = (__hip_bfloat16*)SM_;
    float* G1  = (float*)(SM_ + 36864);
    float* G2  = (float*)(SM_ + 49152);
    float* LG  = (float*)(SM_ + 61440);
    float* LSE = (float*)(SM_ + 62080);
    const float* g = ws + OFF_G;
    if (tid < HH) {
        float s = 0.f, sq = 0.f;
        for (int b = 0; b < BB; ++b) {
            float v = g[b*HH + tid]*(1.f/NN);
            s += v; sq += v*v;
        }
        float mean = s*(1.f/BB), var = sq*(1.f/BB) - mean*mean;
        float a = prm[tid] * rsqrtf(var + EPSV);
        float c = prm[192 + tid] - mean*a;
        for (int b = 0; b < BB; ++b) G1[b*HH + tid] = g[b*HH + tid]*(1.f/NN)*a + c;
    }
    int b = tid >> 5, grp = tid & 31, n0 = grp*6;
    float acc[6];
    #pragma unroll
    for (int e = 0; e < 6; ++e) acc[e] = prm[384 + n0 + e];
    const short8* Wsrc = (const short8*)(ws + OFF_WLT);
    for (int ch = 0; ch < 2; ++ch) {
        __syncthreads();
        for (int i = tid; i < 96*HH/8; i += 512)
            *(short8*)&Wl[8*i] = Wsrc[(size_t)ch*96*HH/8 + i];
        __syncthreads();
        for (int k = 0; k < 96; ++k) {
            float gv = G1[b*HH + ch*96 + k];
            const unsigned int* wp = (const unsigned int*)&Wl[k*HH + n0];
            unsigned int w0 = wp[0], w1 = wp[1], w2 = wp[2];
            acc[0] += gv*blo(w0); acc[1] += gv*bhi(w0);
            acc[2] += gv*blo(w1); acc[3] += gv*bhi(w1);
            acc[4] += gv*blo(w2); acc[5] += gv*bhi(w2);
        }
    }
    __syncthreads();
    #pragma unroll
    for (int e = 0; e < 6; ++e) G2[b*HH + n0 + e] = fmaxf(acc[e], 0.f);
    __syncthreads();
    if (tid < HH) {
        float s = 0.f, sq = 0.f;
        for (int bb = 0; bb < BB; ++bb) { float v = G2[bb*HH + tid]; s += v; sq += v*v; }
        float mean = s*(1.f/BB), var = sq*(1.f/BB) - mean*mean;
        float a = prm[576 + tid] * rsqrtf(var + EPSV);
        float c = prm[768 + tid] - mean*a;
        for (int bb = 0; bb < BB; ++bb) G2[bb*HH + tid] = G2[bb*HH + tid]*a + c;
    }
    __syncthreads();
    if (tid < BB*10) {
        int bb = tid/10, kk = tid%10;
        float a2 = prm[960 + kk];
        for (int h = 0; h < HH; ++h) a2 += G2[bb*HH + h]*prm[976 + h*10 + kk];
        LG[bb*10 + kk] = a2;
    }
    __syncthreads();
    if (tid < BB) {
        float mx = -1e30f;
        for (int k = 0; k < 10; ++k) mx = fmaxf(mx, LG[tid*10 + k]);
        float s = 0.f;
        for (int k = 0; k < 10; ++k) s += expf(LG[tid*10 + k] - mx);
        LSE[tid] = mx + logf(s);
    }
    __syncthreads();
    if (tid < BB*10) {
        int bb = tid/10;
        float v = LG[bb*10 + tid%10] - LSE[bb];
        if (isf) ((float*)out)[tid] = v;
        else     ((__hip_bfloat16*)out)[tid] = __float2bfloat16(v);
    }
}

extern "C" void kernel_launch(void* const* d_in, const int* in_sizes, int n_in,
                              void* d_out, int out_size, void* d_ws, size_t ws_size,
                              hipStream_t stream) {
    const void* x       = d_in[0];
    const void* adj     = d_in[1];
    const void* bnf_g   = d_in[2];
    const void* bnf_b   = d_in[3];
    const void* W_feat  = d_in[4];
    const void* bnc_g   = d_in[5];
    const void* bnc_b   = d_in[6];
    const void* convs_W = d_in[7];
    const void* convs_b = d_in[8];
    const void* fc_g    = d_in[9];
    const void* fc_b    = d_in[10];
    const void* lin_W   = d_in[11];
    const void* lin_b   = d_in[12];
    const void* hid_g   = d_in[13];
    const void* hid_b   = d_in[14];
    const void* cls_W   = d_in[15];
    const void* cls_b   = d_in[16];
    float* ws = (float*)d_ws;

    k_prep<<<192, 512, 0, stream>>>(adj, x, W_feat, convs_W, fc_g, fc_b,
                                    lin_W, lin_b, hid_g, hid_b, cls_W, cls_b,
                                    convs_b, ws);
    k_gg0<<<1024, 512, 0, stream>>>(adj, x, bnf_g, bnf_b, ws);
    for (int l = 0; l < 3; ++l) {
        k_gemmc<<<512, 512, 0, stream>>>(bnc_g, bnc_b, l, ws);
        k_spmm<<<3072, 256, 0, stream>>>(l, ws);
    }
    k_tail<<<1, 512, 0, stream>>>(d_out, ws);
}

// Round 12
// 285.654 us; speedup vs baseline: 1.3495x; 1.0406x over previous
//
#include <hip/hip_runtime.h>
#include <hip/hip_bf16.h>

#define BB 16
#define NN 1024
#define FF 128
#define HH 192
#define NROWS (BB*NN)
#define MAXC 128
#define EPSV 1e-5f

// ---------------- workspace layout (float units) ----------------
constexpr size_t OFF_H0  = 0;                                 // [NROWS*HH] bf16
constexpr size_t OFF_ZB  = OFF_H0 + (size_t)NROWS*HH/2;       // [NROWS*HH] bf16
constexpr size_t OFF_DIS = OFF_ZB + (size_t)NROWS*HH/2;       // [NROWS] f32
constexpr size_t OFF_G   = OFF_DIS + NROWS;                   // [BB*HH] pool sums
constexpr size_t OFF_SH  = OFF_G + BB*HH;                     // 3 stages x 8 buckets x 512
constexpr size_t SH_SIZE = 3*8*512;
constexpr size_t ZERO_SZ = BB*HH + SH_SIZE;                   // zeroed in k_prep
constexpr size_t OFF_FLG = OFF_SH + SH_SIZE;                  // [0] isf flag
constexpr size_t OFF_PRM = OFF_FLG + 16;                      // f32 params [3584]
// prm: 0 fc_g,192 fc_b,384 lin_b,576 hid_g,768 hid_b,960 cls_b(10),
//      976 cls_W(1920), 2896 convs_b(576)
constexpr size_t OFF_WLT = OFF_PRM + 3584;                    // lin_W bf16 [HH*HH]
constexpr size_t OFF_XB  = OFF_WLT + (size_t)HH*HH/2;         // x-stat buckets [128][256]
constexpr size_t OFF_WPF = OFF_XB + 128*256;                  // RAW W_feat^T bf16 [192][128]
constexpr size_t OFF_WPC = OFF_WPF + (size_t)HH*FF/2;         // RAW convs_W^T bf16 [3][192][192]
constexpr size_t OFF_CNT = OFF_WPC + 3*(size_t)HH*HH/2;       // [NROWS] int32
constexpr size_t OFF_COLS= OFF_CNT + NROWS;                   // [NROWS*MAXC] u16

typedef __attribute__((ext_vector_type(8))) short short8;
typedef __attribute__((ext_vector_type(4))) float f32x4;
typedef __attribute__((ext_vector_type(4))) unsigned int u32x4;
typedef __attribute__((ext_vector_type(2))) unsigned int u32x2;

static __device__ __forceinline__ float ldin(const void* p, size_t i, int isf) {
    return isf ? ((const float*)p)[i]
               : __bfloat162float(((const __hip_bfloat16*)p)[i]);
}
static __device__ __forceinline__ float blo(unsigned int u) {
    union { unsigned int x; float f; } v; v.x = u << 16; return v.f;
}
static __device__ __forceinline__ float bhi(unsigned int u) {
    union { unsigned int x; float f; } v; v.x = u & 0xFFFF0000u; return v.f;
}
static __device__ __forceinline__ unsigned int packbf(float a, float b) {
    union { unsigned int u; __hip_bfloat16 h[2]; } p;
    p.h[0] = __float2bfloat16(a); p.h[1] = __float2bfloat16(b);
    return p.u;
}
static __device__ __forceinline__ unsigned short bf16bits(float a) {
    union { unsigned short u; __hip_bfloat16 h; } p;
    p.h = __float2bfloat16(a); return p.u;
}
static __device__ __forceinline__ int rdflag(const float* ws) {
    return ((const int*)(ws + OFF_FLG))[0];
}

// dtype self-detection — run ONLY inside k_prep; published to ws flag.
template<int T>
static __device__ __forceinline__ int detect_isf(const unsigned int* __restrict__ adjw,
                                                 int tid, int* sh_flag) {
    if (tid == 0) *sh_flag = 0;
    __syncthreads();
    int hit = 0;
    for (int k = tid; k < 1024; k += T)
        if ((adjw[k] & 0xFFFFu) == 0x3F80u) hit = 1;
    if (hit) *sh_flag = 1;
    __syncthreads();
    return (*sh_flag == 0) ? 1 : 0;
}

// ---- graph row via per-lane hitmask + wave prefix-scan (no ballot chain) ---
// Lane handles 16 CONSECUTIVE elems (coalesced 64B/32B). Output order and
// counts are bit-identical to the serial-ballot version (ascending j).
static __device__ __forceinline__ void graph_row_scan(int row, int lane, int isf,
                                                      const void* adj, float* ws) {
    int irow = row & (NN - 1);
    int j0 = lane*16;
    unsigned int hm = 0;                              // 16-bit hitmask
    if (isf) {
        const unsigned int* ap = (const unsigned int*)adj + (size_t)row*NN + j0;
        u32x4 v0 = *(const u32x4*)ap;
        u32x4 v1 = *(const u32x4*)(ap + 4);
        u32x4 v2 = *(const u32x4*)(ap + 8);
        u32x4 v3 = *(const u32x4*)(ap + 12);
        unsigned int w[16] = {v0[0],v0[1],v0[2],v0[3], v1[0],v1[1],v1[2],v1[3],
                              v2[0],v2[1],v2[2],v2[3], v3[0],v3[1],v3[2],v3[3]};
        #pragma unroll
        for (int e = 0; e < 16; ++e)
            if ((w[e] << 1) != 0u) hm |= 1u << e;
    } else {
        const unsigned int* ap = (const unsigned int*)
            ((const unsigned short*)adj + (size_t)row*NN + j0);
        u32x4 v0 = *(const u32x4*)ap;
        u32x4 v1 = *(const u32x4*)(ap + 4);
        unsigned int w[8] = {v0[0],v0[1],v0[2],v0[3], v1[0],v1[1],v1[2],v1[3]};
        #pragma unroll
        for (int e = 0; e < 8; ++e) {
            if ((w[e] & 0x7FFFu)     != 0u) hm |= 1u << (2*e);
            if (((w[e] >> 16) & 0x7FFFu) != 0u) hm |= 1u << (2*e + 1);
        }
    }
    if (irow >= j0 && irow < j0 + 16) hm |= 1u << (irow - j0);  // self loop
    int n = __popc(hm);
    int s = n;                                        // 6-step inclusive scan
    #pragma unroll
    for (int d = 1; d < 64; d <<= 1) {
        int t = __shfl_up(s, d, 64);
        if (lane >= d) s += t;
    }
    int p = s - n;                                    // exclusive offset
    int total = __shfl(s, 63, 64);
    unsigned short* cols = (unsigned short*)(ws + OFF_COLS) + (size_t)row*MAXC;
    unsigned int mrem = hm;
    while (mrem) {
        int b = __ffs(mrem) - 1;
        if (p < MAXC) cols[p] = (unsigned short)(j0 + b);
        mrem &= mrem - 1;
        ++p;
    }
    if (lane == 0) {
        ((int*)(ws + OFF_CNT))[row] = total > MAXC ? MAXC : total;
        ws[OFF_DIS + row] = rsqrtf((float)total);     // deg >= 1 (self loop)
    }
}

// ================= K1: detect + zero + x-stats + copies + graph =============
// grid 704: bid<128 x-stats; 128<=bid<192 zero/copies/W-conversions;
//           bid>=192: prefix-scan graph build (512 blocks x 32 rows).
__global__ __launch_bounds__(512) void k_prep(const void* __restrict__ adj,
        const void* __restrict__ x,
        const void* __restrict__ W_feat, const void* __restrict__ convs_W,
        const void* __restrict__ fc_g, const void* __restrict__ fc_b,
        const void* __restrict__ lin_W, const void* __restrict__ lin_b,
        const void* __restrict__ hid_g, const void* __restrict__ hid_b,
        const void* __restrict__ cls_W, const void* __restrict__ cls_b,
        const void* __restrict__ convs_b, float* ws) {
    __shared__ __align__(16) float XS[1024];
    __shared__ int sflag;
    int tid = threadIdx.x, bid = blockIdx.x;
    const int isf = detect_isf<512>((const unsigned int*)adj, tid, &sflag);
    if (bid < 128) {
        int f = tid & 127, part = tid >> 7;           // 4 parts x 32 rows
        int r0 = bid*128 + part*32;
        float s = 0.f, q = 0.f;
        for (int r = 0; r < 32; ++r) {
            float v = ldin(x, (size_t)(r0 + r)*FF + f, isf);
            s += v; q += v*v;
        }
        XS[part*128 + f] = s; XS[512 + part*128 + f] = q;
        __syncthreads();
        if (part == 0) {
            ws[OFF_XB + (size_t)bid*256 + f] =
                XS[f] + XS[128+f] + XS[256+f] + XS[384+f];
            ws[OFF_XB + (size_t)bid*256 + 128 + f] =
                XS[512+f] + XS[640+f] + XS[768+f] + XS[896+f];
        }
    } else if (bid < 192) {
        int gid = (bid - 128)*512 + tid;              // 0..32767
        if (gid < 16) ((int*)(ws + OFF_FLG))[gid] = (gid == 0) ? isf : 0;
        for (size_t i = gid; i < ZERO_SZ; i += 32768) ws[OFF_G + i] = 0.f;
        float* prm = ws + OFF_PRM;
        if (gid < 192) {
            prm[gid]       = ldin(fc_g,  gid, isf);
            prm[192 + gid] = ldin(fc_b,  gid, isf);
            prm[384 + gid] = ldin(lin_b, gid, isf);
            prm[576 + gid] = ldin(hid_g, gid, isf);
            prm[768 + gid] = ldin(hid_b, gid, isf);
        }
        if (gid < 10)   prm[960 + gid]  = ldin(cls_b, gid, isf);
        if (gid < 1920) prm[976 + gid]  = ldin(cls_W, gid, isf);
        if (gid < 576)  prm[2896 + gid] = ldin(convs_b, gid, isf);
        unsigned short* wlt = (unsigned short*)(ws + OFF_WLT);
        for (int i = gid; i < HH*HH; i += 32768)
            wlt[i] = bf16bits(ldin(lin_W, i, isf));
        // raw W^T conversions (coalesced read, scattered 2B write -> L2)
        unsigned short* wpf = (unsigned short*)(ws + OFF_WPF);
        if (gid < FF*HH) {                            // 24576
            int k = gid / HH, n = gid - k*HH;
            wpf[(size_t)n*FF + k] = bf16bits(ldin(W_feat, (size_t)k*HH + n, isf));
        }
        unsigned short* wpc = (unsigned short*)(ws + OFF_WPC);
        for (int i = gid; i < 3*HH*HH; i += 32768) {  // 110592
            int l = i / (HH*HH), r2 = i - l*HH*HH;
            int k = r2 / HH, n = r2 - k*HH;
            wpc[(size_t)l*HH*HH + (size_t)n*HH + k] =
                bf16bits(ldin(convs_W, (size_t)l*HH*HH + (size_t)k*HH + n, isf));
        }
    } else {
        int gb = bid - 192;
        int wv = tid >> 6, lane = tid & 63;
        #pragma unroll
        for (int rr = 0; rr < 4; ++rr)
            graph_row_scan(gb*32 + wv*4 + rr, lane, isf, adj, ws);
    }
}

// ================= K2: gemm0 with in-register A-side BN fold ================
// A' = a_k*x + c_k (regs) -> A'@W already includes the c-term; NO extra bias.
__global__ __launch_bounds__(512, 4) void k_gemm0(const void* __restrict__ x,
        const void* __restrict__ gg, const void* __restrict__ bb,
        float* __restrict__ ws) {
    __shared__ __align__(16) float AF[FF], CF[FF], SH2[384];
    int tid = threadIdx.x, bid = blockIdx.x;
    const int isf = rdflag(ws);
    if (tid < FF) {
        float s = 0.f, q = 0.f;
        for (int b = 0; b < 128; ++b) {
            s += ws[OFF_XB + (size_t)b*256 + tid];
            q += ws[OFF_XB + (size_t)b*256 + 128 + tid];
        }
        float mean = s*(1.f/NROWS), var = q*(1.f/NROWS) - mean*mean;
        float a = ldin(gg, tid, isf) * rsqrtf(var + EPSV);
        AF[tid] = a;
        CF[tid] = ldin(bb, tid, isf) - mean*a;
    }
    for (int i = tid; i < 384; i += 512) SH2[i] = 0.f;
    __syncthreads();
    const __hip_bfloat16* BT = (const __hip_bfloat16*)(ws + OFF_WPF);
    int lane = tid & 63, w8 = tid >> 6;
    int wr = w8 & 1, wc = w8 >> 1;
    int m = lane & 15, quad = lane >> 4;
    int batch = bid & 15, seg = bid >> 4;
    int row0 = batch*NN + seg*32;
    int rowA = row0 + wr*16 + m;
    f32x4 acc[3];
    #pragma unroll
    for (int tt = 0; tt < 3; ++tt) acc[tt] = f32x4{0.f,0.f,0.f,0.f};
    #pragma unroll
    for (int kb = 0; kb < FF/32; ++kb) {
        int k0 = kb*32 + quad*8;
        float xv[8];
        if (isf) {
            const float* Ar = (const float*)x + (size_t)rowA*FF + k0;
            f32x4 v0 = *(const f32x4*)Ar, v1 = *(const f32x4*)(Ar + 4);
            #pragma unroll
            for (int e = 0; e < 4; ++e) { xv[e] = v0[e]; xv[4+e] = v1[e]; }
        } else {
            union { short8 s8; __hip_bfloat16 h[8]; } u;
            u.s8 = *(const short8*)((const __hip_bfloat16*)x + (size_t)rowA*FF + k0);
            #pragma unroll
            for (int e = 0; e < 8; ++e) xv[e] = __bfloat162float(u.h[e]);
        }
        union { short8 s8; __hip_bfloat16 h[8]; } ua;
        #pragma unroll
        for (int e = 0; e < 8; ++e)
            ua.h[e] = __float2bfloat16(AF[k0+e]*xv[e] + CF[k0+e]);
        short8 a = ua.s8;
        #pragma unroll
        for (int tt = 0; tt < 3; ++tt) {
            short8 b = *(const short8*)(BT + (size_t)(wc*48 + tt*16 + m)*FF + k0);
            acc[tt] = __builtin_amdgcn_mfma_f32_16x16x32_bf16(a, b, acc[tt], 0, 0, 0);
        }
    }
    __hip_bfloat16* H0 = (__hip_bfloat16*)(ws + OFF_H0);
    #pragma unroll
    for (int tt = 0; tt < 3; ++tt) {
        int nl = wc*48 + tt*16 + m;
        float s = 0.f, sq = 0.f;
        #pragma unroll
        for (int r = 0; r < 4; ++r) {
            int row = row0 + wr*16 + quad*4 + r;
            float o = fmaxf(acc[tt][r], 0.f);         // c-term is inside A'@W
            H0[(size_t)row*HH + nl] = __float2bfloat16(o);
            s += o; sq += o*o;
        }
        s  += __shfl_xor(s, 16, 64);  s  += __shfl_xor(s, 32, 64);
        sq += __shfl_xor(sq, 16, 64); sq += __shfl_xor(sq, 32, 64);
        if (quad == 0) {
            atomicAdd(&SH2[nl], s);
            atomicAdd(&SH2[192 + nl], sq);
        }
    }
    __syncthreads();
    float* st = ws + OFF_SH + (size_t)(bid & 7)*512;
    if (tid < 192) {
        atomicAdd(&st[tid], SH2[tid]);
        atomicAdd(&st[256 + tid], SH2[192 + tid]);
    }
}

// ================= K per-layer: conv gemm with A-side BN fold ===============
__global__ __launch_bounds__(512, 4) void k_gemmc(const void* __restrict__ gg,
        const void* __restrict__ bb, int layer, float* __restrict__ ws) {
    __shared__ __align__(16) float AF[HH], CF[HH];
    __shared__ __align__(16) unsigned short ZT[32*HH];   // 12 KB
    int tid = threadIdx.x, bid = blockIdx.x;
    const int isf = rdflag(ws);
    if (tid < HH) {
        const float* st = ws + OFF_SH + (size_t)layer*4096;
        float s = 0.f, q = 0.f;
        #pragma unroll
        for (int b = 0; b < 8; ++b) {
            s += st[b*512 + tid];
            q += st[b*512 + 256 + tid];
        }
        float mean = s*(1.f/NROWS), var = q*(1.f/NROWS) - mean*mean;
        float a = ldin(gg, (size_t)layer*HH + tid, isf) * rsqrtf(var + EPSV);
        AF[tid] = a;
        CF[tid] = ldin(bb, (size_t)layer*HH + tid, isf) - mean*a;
    }
    __syncthreads();
    const __hip_bfloat16* BT = (const __hip_bfloat16*)(ws + OFF_WPC) +
                               (size_t)layer*HH*HH;
    int lane = tid & 63, w8 = tid >> 6;
    int wr = w8 & 1, wc = w8 >> 1;
    int m = lane & 15, quad = lane >> 4;
    int batch = bid & 15, seg = bid >> 4;
    int row0 = batch*NN + seg*32;
    int rowA = row0 + wr*16 + m;
    const __hip_bfloat16* A = (const __hip_bfloat16*)(ws + OFF_H0);
    f32x4 acc[3];
    #pragma unroll
    for (int tt = 0; tt < 3; ++tt) acc[tt] = f32x4{0.f,0.f,0.f,0.f};
    #pragma unroll
    for (int kb = 0; kb < HH/32; ++kb) {
        int k0 = kb*32 + quad*8;
        union { short8 s8; __hip_bfloat16 h[8]; } u;
        u.s8 = *(const short8*)(A + (size_t)rowA*HH + k0);
        union { short8 s8; __hip_bfloat16 h[8]; } ua;
        #pragma unroll
        for (int e = 0; e < 8; ++e)
            ua.h[e] = __float2bfloat16(AF[k0+e]*__bfloat162float(u.h[e]) + CF[k0+e]);
        short8 a = ua.s8;
        #pragma unroll
        for (int tt = 0; tt < 3; ++tt) {
            short8 b = *(const short8*)(BT + (size_t)(wc*48 + tt*16 + m)*HH + k0);
            acc[tt] = __builtin_amdgcn_mfma_f32_16x16x32_bf16(a, b, acc[tt], 0, 0, 0);
        }
    }
    const float* dis = ws + OFF_DIS;
    float sc[4];
    #pragma unroll
    for (int r = 0; r < 4; ++r) sc[r] = dis[row0 + wr*16 + quad*4 + r];
    #pragma unroll
    for (int tt = 0; tt < 3; ++tt) {
        int nl = wc*48 + tt*16 + m;
        #pragma unroll
        for (int r = 0; r < 4; ++r)
            ZT[(wr*16 + quad*4 + r)*HH + nl] = bf16bits(acc[tt][r]*sc[r]);
    }
    __syncthreads();
    unsigned int* Zg = (unsigned int*)(ws + OFF_ZB) + (size_t)row0*96;
    const unsigned int* ZTu = (const unsigned int*)ZT;
    #pragma unroll
    for (int ii = 0; ii < 3; ++ii) {
        int i = tid + ii*512;
        *(u32x2*)(&Zg[2*i]) = *(const u32x2*)(&ZTu[2*i]);
    }
}

// ================= K per-layer: spmm direct-from-L2 =========================
__global__ __launch_bounds__(256, 6) void k_spmm(int layer, float* __restrict__ ws) {
    __shared__ float SH[64];
    int tid = threadIdx.x, bid = blockIdx.x;
    for (int i = tid; i < 64; i += 256) SH[i] = 0.f;
    int batch = bid / 192, rem = bid - batch*192;
    int slice = rem >> 5, rg = rem & 31;
    int u = tid >> 3, d = tid & 7;
    int row = batch*NN + rg*32 + u;
    int c0 = slice*32;
    int base = slice*16 + d*2;
    const int c = ((const int*)(ws + OFF_CNT))[row];
    const unsigned short* cl = (const unsigned short*)(ws + OFF_COLS) + (size_t)row*MAXC;
    const unsigned int* Zb = (const unsigned int*)(ws + OFF_ZB) + (size_t)batch*NN*96;
    float bch[4];
    #pragma unroll
    for (int e = 0; e < 4; ++e)
        bch[e] = ws[OFF_PRM + 2896 + (size_t)layer*HH + c0 + d*4 + e];
    float a0=0.f, a1=0.f, a2=0.f, a3=0.f;
    int k = 0;
    for (; k + 8 <= c; k += 8) {
        u32x4 cw = *(const u32x4*)(cl + k);
        int j[8];
        j[0]=(int)(cw[0]&0xFFFFu); j[1]=(int)(cw[0]>>16);
        j[2]=(int)(cw[1]&0xFFFFu); j[3]=(int)(cw[1]>>16);
        j[4]=(int)(cw[2]&0xFFFFu); j[5]=(int)(cw[2]>>16);
        j[6]=(int)(cw[3]&0xFFFFu); j[7]=(int)(cw[3]>>16);
        u32x2 z[8];
        #pragma unroll
        for (int e = 0; e < 8; ++e)
            z[e] = *(const u32x2*)(&Zb[(size_t)j[e]*96 + base]);
        #pragma unroll
        for (int e = 0; e < 8; ++e) {
            a0 += blo(z[e][0]); a1 += bhi(z[e][0]);
            a2 += blo(z[e][1]); a3 += bhi(z[e][1]);
        }
    }
    for (; k < c; ++k) {
        u32x2 z = *(const u32x2*)(&Zb[(size_t)cl[k]*96 + base]);
        a0 += blo(z[0]); a1 += bhi(z[0]);
        a2 += blo(z[1]); a3 += bhi(z[1]);
    }
    float dd = ws[OFF_DIS + row];
    float o0 = fmaxf(dd*a0 + bch[0], 0.f);
    float o1 = fmaxf(dd*a1 + bch[1], 0.f);
    float o2 = fmaxf(dd*a2 + bch[2], 0.f);
    float o3 = fmaxf(dd*a3 + bch[3], 0.f);
    unsigned int* H0u = (unsigned int*)(ws + OFF_H0);
    u32x2 outw; outw[0] = packbf(o0,o1); outw[1] = packbf(o2,o3);
    *(u32x2*)(&H0u[(size_t)row*96 + base]) = outw;
    float s_acc[4] = {o0,o1,o2,o3};
    float q_acc[4] = {o0*o0,o1*o1,o2*o2,o3*o3};
    const int is_pool = (layer == 2);
    #pragma unroll
    for (int e = 0; e < 4; ++e) {
        #pragma unroll
        for (int mask = 8; mask < 64; mask <<= 1) {
            s_acc[e] += __shfl_xor(s_acc[e], mask, 64);
            if (!is_pool) q_acc[e] += __shfl_xor(q_acc[e], mask, 64);
        }
    }
    __syncthreads();
    if ((tid & 63) < 8) {
        #pragma unroll
        for (int e = 0; e < 4; ++e) {
            atomicAdd(&SH[d*4 + e], s_acc[e]);
            if (!is_pool) atomicAdd(&SH[32 + d*4 + e], q_acc[e]);
        }
    }
    __syncthreads();
    if (tid < 32) {
        if (is_pool) {
            atomicAdd(&ws[OFF_G + (size_t)batch*HH + c0 + tid], SH[tid]);
        } else {
            float* st = ws + OFF_SH + (size_t)(layer + 1)*4096 + (size_t)(bid & 7)*512;
            atomicAdd(&st[c0 + tid],       SH[tid]);
            atomicAdd(&st[256 + c0 + tid], SH[32 + tid]);
        }
    }
}

// ================= tail (separate launch; params from ws) ===================
__global__ __launch_bounds__(512) void k_tail(void* __restrict__ out,
                                              const float* __restrict__ ws) {
    __shared__ __align__(16) char SM_[62144];
    int tid = threadIdx.x;
    const int isf = rdflag(ws);
    const float* prm = ws + OFF_PRM;
    __hip_bfloat16* Wl = (__hip_bfloat16*)SM_;
    float* G1  = (float*)(SM_ + 36864);
    float* G2  = (float*)(SM_ + 49152);
    float* LG  = (float*)(SM_ + 61440);
    float* LSE = (float*)(SM_ + 62080);
    const float* g = ws + OFF_G;
    if (tid < HH) {
        float s = 0.f, sq = 0.f;
        for (int b = 0; b < BB; ++b) {
            float v = g[b*HH + tid]*(1.f/NN);
            s += v; sq += v*v;
        }
        float mean = s*(1.f/BB), var = sq*(1.f/BB) - mean*mean;
        float a = prm[tid] * rsqrtf(var + EPSV);
        float c = prm[192 + tid] - mean*a;
        for (int b = 0; b < BB; ++b) G1[b*HH + tid] = g[b*HH + tid]*(1.f/NN)*a + c;
    }
    int b = tid >> 5, grp = tid & 31, n0 = grp*6;
    float acc[6];
    #pragma unroll
    for (int e = 0; e < 6; ++e) acc[e] = prm[384 + n0 + e];
    const short8* Wsrc = (const short8*)(ws + OFF_WLT);
    for (int ch = 0; ch < 2; ++ch) {
        __syncthreads();
        for (int i = tid; i < 96*HH/8; i += 512)
            *(short8*)&Wl[8*i] = Wsrc[(size_t)ch*96*HH/8 + i];
        __syncthreads();
        for (int k = 0; k < 96; ++k) {
            float gv = G1[b*HH + ch*96 + k];
            const unsigned int* wp = (const unsigned int*)&Wl[k*HH + n0];
            unsigned int w0 = wp[0], w1 = wp[1], w2 = wp[2];
            acc[0] += gv*blo(w0); acc[1] += gv*bhi(w0);
            acc[2] += gv*blo(w1); acc[3] += gv*bhi(w1);
            acc[4] += gv*blo(w2); acc[5] += gv*bhi(w2);
        }
    }
    __syncthreads();
    #pragma unroll
    for (int e = 0; e < 6; ++e) G2[b*HH + n0 + e] = fmaxf(acc[e], 0.f);
    __syncthreads();
    if (tid < HH) {
        float s = 0.f, sq = 0.f;
        for (int bb = 0; bb < BB; ++bb) { float v = G2[bb*HH + tid]; s += v; sq += v*v; }
        float mean = s*(1.f/BB), var = sq*(1.f/BB) - mean*mean;
        float a = prm[576 + tid] * rsqrtf(var + EPSV);
        float c = prm[768 + tid] - mean*a;
        for (int bb = 0; bb < BB; ++bb) G2[bb*HH + tid] = G2[bb*HH + tid]*a + c;
    }
    __syncthreads();
    if (tid < BB*10) {
        int bb = tid/10, kk = tid%10;
        float a2 = prm[960 + kk];
        for (int h = 0; h < HH; ++h) a2 += G2[bb*HH + h]*prm[976 + h*10 + kk];
        LG[bb*10 + kk] = a2;
    }
    __syncthreads();
    if (tid < BB) {
        float mx = -1e30f;
        for (int k = 0; k < 10; ++k) mx = fmaxf(mx, LG[tid*10 + k]);
        float s = 0.f;
        for (int k = 0; k < 10; ++k) s += expf(LG[tid*10 + k] - mx);
        LSE[tid] = mx + logf(s);
    }
    __syncthreads();
    if (tid < BB*10) {
        int bb = tid/10;
        float v = LG[bb*10 + tid%10] - LSE[bb];
        if (isf) ((float*)out)[tid] = v;
        else     ((__hip_bfloat16*)out)[tid] = __float2bfloat16(v);
    }
}

extern "C" void kernel_launch(void* const* d_in, const int* in_sizes, int n_in,
                              void* d_out, int out_size, void* d_ws, size_t ws_size,
                              hipStream_t stream) {
    const void* x       = d_in[0];
    const void* adj     = d_in[1];
    const void* bnf_g   = d_in[2];
    const void* bnf_b   = d_in[3];
    const void* W_feat  = d_in[4];
    const void* bnc_g   = d_in[5];
    const void* bnc_b   = d_in[6];
    const void* convs_W = d_in[7];
    const void* convs_b = d_in[8];
    const void* fc_g    = d_in[9];
    const void* fc_b    = d_in[10];
    const void* lin_W   = d_in[11];
    const void* lin_b   = d_in[12];
    const void* hid_g   = d_in[13];
    const void* hid_b   = d_in[14];
    const void* cls_W   = d_in[15];
    const void* cls_b   = d_in[16];
    float* ws = (float*)d_ws;

    k_prep<<<704, 512, 0, stream>>>(adj, x, W_feat, convs_W, fc_g, fc_b,
                                    lin_W, lin_b, hid_g, hid_b, cls_W, cls_b,
                                    convs_b, ws);
    k_gemm0<<<512, 512, 0, stream>>>(x, bnf_g, bnf_b, ws);
    for (int l = 0; l < 3; ++l) {
        k_gemmc<<<512, 512, 0, stream>>>(bnc_g, bnc_b, l, ws);
        k_spmm<<<3072, 256, 0, stream>>>(l, ws);
    }
    k_tail<<<1, 512, 0, stream>>>(d_out, ws);
}